// Round 12
// baseline (89.393 us; speedup 1.0000x reference)
//
#include <hip/hip_runtime.h>
#include <stdint.h>

// DSVDD fused: dist = sqrt(||phi||^2 + ||c||^2 - 2 phi.c), top-3 smallest, softmin score.
// bf16 MFMA computes S = phi.c - ||c||^2/2 (centers folded into K-pad 112->128),
// track top-3 LARGEST S per row == 3 smallest distances.
// R12 = R11 with the compile fix: __builtin_nontemporal_load needs a NATIVE vector type
// (ext_vector_type(4) float), not HIP's float4 class. Theory unchanged: nt phi loads
// keep CT2 L2-resident so the af stream is served at L2 latency, which the 1-tile
// double buffer can hide.

typedef short s16x8 __attribute__((ext_vector_type(8)));
typedef float fx4 __attribute__((ext_vector_type(4)));
typedef float f32x4 __attribute__((ext_vector_type(4)));  // native vec for nt builtins

#define M_TOT 3136
#define CC 112
#define NROWS 50176
#define N_TILES_TOT 50  // 3200 m / 64 per tile; tile bytes = 64*256 = 16384

__device__ __forceinline__ unsigned short f2bf(float x) {
  unsigned u = __float_as_uint(x);
  u += 0x7fffu + ((u >> 16) & 1u);  // RNE
  return (unsigned short)(u >> 16);
}

// insert v into descending triple (t0 >= t1 >= t2), keep 3 largest. 3 VALU ops.
#define INSERT3(T0, T1, T2, V)                                  \
  do {                                                          \
    const float _a0 = (T0), _a1 = (T1), _v = (V);               \
    (T0) = fmaxf(_a0, _v);                                      \
    (T1) = __builtin_amdgcn_fmed3f(_a0, _a1, _v);               \
    (T2) = __builtin_amdgcn_fmed3f(_a1, (T2), _v);              \
  } while (0)

// ---- prep: CT2[tile][f][ks][lane] 16B slots, fragment-ordered for MFMA A-operand ----
// slot value: 8 bf16 = CT[m = tile*64+f*16+(lane&15)][k = ks*32+(lane>>4)*8 + 0..7]
// where CT[m][k] = C_bank[k][m] (k<112); -||c_m||^2/8 (112<=k<116, sentinel -2500); 0 else.
__global__ __launch_bounds__(256) void dsvdd_prep(const float* __restrict__ Cb,
                                                  unsigned char* __restrict__ CT2) {
  const int tile = blockIdx.x;
  __shared__ float partial[256];
  __shared__ float c2s[64];  // pre-scaled fold value per local m
  const int tm = threadIdx.x & 63;
  const int seg = threadIdx.x >> 6;
  const int m = tile * 64 + tm;
  float ss = 0.f;
  if (m < M_TOT) {
    for (int k = seg * 28; k < seg * 28 + 28; ++k) {
      const float x = Cb[(size_t)k * M_TOT + m];
      ss += x * x;
    }
  }
  partial[threadIdx.x] = ss;
  __syncthreads();
  if (seg == 0) {
    const float c2 = partial[tm] + partial[64 + tm] + partial[128 + tm] + partial[192 + tm];
    c2s[tm] = (m < M_TOT) ? (-0.125f * c2) : -2500.0f;  // sentinel: S ~ -1e4
  }
  __syncthreads();
#pragma unroll
  for (int it = 0; it < 4; ++it) {
    const int s = it * 256 + threadIdx.x;  // 0..1023 slots per tile
    const int f = s >> 8;
    const int ks = (s >> 6) & 3;
    const int l = s & 63;
    const int mloc = f * 16 + (l & 15);
    const int mm = tile * 64 + mloc;
    const bool mv = (mm < M_TOT);
    const int k0 = ks * 32 + (l >> 4) * 8;
    float v[8];
#pragma unroll
    for (int j = 0; j < 8; ++j) {
      const int k = k0 + j;
      float x = 0.f;
      if (k < CC) x = mv ? Cb[(size_t)k * M_TOT + mm] : 0.f;
      else if (k < 116) x = c2s[mloc];
      v[j] = x;
    }
    uint4 pk;
    pk.x = (unsigned)f2bf(v[0]) | ((unsigned)f2bf(v[1]) << 16);
    pk.y = (unsigned)f2bf(v[2]) | ((unsigned)f2bf(v[3]) << 16);
    pk.z = (unsigned)f2bf(v[4]) | ((unsigned)f2bf(v[5]) << 16);
    pk.w = (unsigned)f2bf(v[6]) | ((unsigned)f2bf(v[7]) << 16);
    *(uint4*)(CT2 + (size_t)tile * 16384 + (size_t)s * 16) = pk;
  }
}

// ---- stage1: block = 128 rows x nT tiles of 64 m; 4 waves = 2 row-groups x 2 m-halves.
// Barrier-free main loop: each wave streams its 2 fragments (8 coalesced 1KB loads/tile)
// global->reg from L2 (CT2 stays L2-resident thanks to nt phi loads), double-buffered.
__global__ __launch_bounds__(256, 3) void dsvdd_stage1(const float* __restrict__ phi,
                                                       const unsigned char* __restrict__ CT2,
                                                       float* __restrict__ part,
                                                       float* __restrict__ featg, int nT) {
  // phi fragments staged in fragment order [g][pf][ks][lane]x16B = 32KB;
  // aliased by the 4KB epilogue merge scratch after extraction.
  __shared__ __align__(16) unsigned char phiF[32768];
  float(*const mg)[8] = (float(*)[8])phiF;

  const int t = threadIdx.x;
  const int lane = t & 63;
  const int w = t >> 6;
  const int g = w >> 1;  // row-group: rows [g*64, g*64+64)
  const int h = w & 1;   // m-half: fragments f = h*2, h*2+1
  const int cq = lane & 15;
  const int kq = lane >> 4;
  const int c = blockIdx.y;
  const int tile0 = c * nT;
  const long rowBase = (long)blockIdx.x * 128;
  const bool needF = (c == 0);

  // ---- coalesced phi prologue (NON-TEMPORAL): 2 threads/row read 448B runs ----
  {
    const int r = t >> 1;
    const int h2 = t & 1;
    const float* src = phi + (size_t)(rowBase + r) * CC + h2 * 56;
    unsigned char* const base = phiF + (((r >> 4) * 4) * 1024);  // (g*4+pf) = r>>4
    const int pcq = r & 15;
    float ss = 0.f;
#pragma unroll
    for (int j = 0; j < 7; ++j) {
      const int k0 = h2 * 56 + j * 8;
      const int ks = k0 >> 5;
      const int kqw = (k0 >> 3) & 3;
      const f32x4 a = __builtin_nontemporal_load((const f32x4*)(src + j * 8));
      const f32x4 b = __builtin_nontemporal_load((const f32x4*)(src + j * 8 + 4));
      ss += a.x * a.x + a.y * a.y + a.z * a.z + a.w * a.w;
      ss += b.x * b.x + b.y * b.y + b.z * b.z + b.w * b.w;
      uint4 pk;
      pk.x = (unsigned)f2bf(a.x) | ((unsigned)f2bf(a.y) << 16);
      pk.y = (unsigned)f2bf(a.z) | ((unsigned)f2bf(a.w) << 16);
      pk.z = (unsigned)f2bf(b.x) | ((unsigned)f2bf(b.y) << 16);
      pk.w = (unsigned)f2bf(b.z) | ((unsigned)f2bf(b.w) << 16);
      *(uint4*)(base + ks * 1024 + (kqw * 16 + pcq) * 16) = pk;
    }
    {  // K-pad: h2==0 -> fold slot (ks=3,kq=2) = {1,1,1,1,0,0,0,0}; h2==1 -> (3,3)=0
      uint4 pk;
      if (h2 == 0) { pk.x = 0x3f803f80u; pk.y = 0x3f803f80u; pk.z = 0u; pk.w = 0u; }
      else { pk.x = pk.y = pk.z = pk.w = 0u; }
      *(uint4*)(base + 3 * 1024 + ((2 + h2) * 16 + pcq) * 16) = pk;
    }
    ss += __shfl_xor(ss, 1);
    if (needF && h2 == 0) __builtin_nontemporal_store(ss, &featg[rowBase + r]);
  }
  __syncthreads();

  // ---- extract bg fragments: contiguous conflict-free ds_read_b128 ----
  s16x8 bg[4][4];  // [ks][pf]
#pragma unroll
  for (int ks = 0; ks < 4; ++ks)
#pragma unroll
    for (int pf = 0; pf < 4; ++pf)
      bg[ks][pf] = *(const s16x8*)(phiF + (((g * 4 + pf) * 4 + ks) * 64 + lane) * 16);
  __syncthreads();  // all reads done before mg alias is written in the epilogue

  float t0[4], t1[4], t2[4];
#pragma unroll
  for (int pf = 0; pf < 4; ++pf) t0[pf] = t1[pf] = t2[pf] = -3.0e38f;

  // ---- barrier-free main loop, tile order rotated by blockIdx.x % nT ----
  // af fragment load: CT2 + tile*16384 + (f*4+ks)*1024 + lane*16, f = h*2+mf
  const unsigned char* ap = CT2 + (size_t)(h * 2) * 4096 + (size_t)lane * 16;
  s16x8 afA[8], afB[8];  // named double buffers (compile-time indexed -> registers)

#define NXJ(J) ((J) + 1 < nT ? (J) + 1 : 0)
#define LOADAF(DST, TIDX)                                                     \
  do {                                                                        \
    const unsigned char* _p = ap + (size_t)(TIDX)*16384;                      \
    _Pragma("unroll") for (int mf = 0; mf < 2; ++mf)                          \
        _Pragma("unroll") for (int ks = 0; ks < 4; ++ks)                      \
            DST[mf * 4 + ks] = *(const s16x8*)(_p + mf * 4096 + ks * 1024);   \
  } while (0)

#define COMPUTE(SRC)                                                          \
  do {                                                                        \
    const fx4 _zz = {0.f, 0.f, 0.f, 0.f};                                     \
    _Pragma("unroll") for (int mf = 0; mf < 2; ++mf) {                        \
      fx4 acc[4];                                                             \
      _Pragma("unroll") for (int ks = 0; ks < 4; ++ks)                        \
          _Pragma("unroll") for (int pf = 0; pf < 4; ++pf)                    \
              acc[pf] = __builtin_amdgcn_mfma_f32_16x16x32_bf16(              \
                  SRC[mf * 4 + ks], bg[ks][pf], (ks == 0) ? _zz : acc[pf],    \
                  0, 0, 0);                                                   \
      _Pragma("unroll") for (int pf = 0; pf < 4; ++pf)                        \
          _Pragma("unroll") for (int rg = 0; rg < 4; ++rg)                    \
              INSERT3(t0[pf], t1[pf], t2[pf], acc[pf][rg]);                   \
    }                                                                         \
  } while (0)

  int j = (int)blockIdx.x % nT;  // staggered start tile within this chunk
  LOADAF(afA, tile0 + j); j = NXJ(j);
  int tt = 0;
  while (tt + 2 < nT) {
    LOADAF(afB, tile0 + j); j = NXJ(j);
    COMPUTE(afA);
    LOADAF(afA, tile0 + j); j = NXJ(j);
    COMPUTE(afB);
    tt += 2;
  }
  if (tt + 1 < nT) {  // even nT: one pair left
    LOADAF(afB, tile0 + j);
    COMPUTE(afA);
    COMPUTE(afB);
  } else {  // odd nT: single tile left
    COMPUTE(afA);
  }
#undef LOADAF
#undef COMPUTE
#undef NXJ

  // ---- merge the 4 kq groups within each wave ----
#pragma unroll
  for (int pf = 0; pf < 4; ++pf) {
#pragma unroll
    for (int off = 16; off < 64; off <<= 1) {
      const float b0 = __shfl_xor(t0[pf], off);
      const float b1 = __shfl_xor(t1[pf], off);
      const float b2 = __shfl_xor(t2[pf], off);
      INSERT3(t0[pf], t1[pf], t2[pf], b0);
      INSERT3(t0[pf], t1[pf], t2[pf], b1);
      INSERT3(t0[pf], t1[pf], t2[pf], b2);
    }
  }
  if (kq == 0) {
#pragma unroll
    for (int pf = 0; pf < 4; ++pf) {
      const int row = g * 64 + pf * 16 + cq;
      mg[row][h * 3 + 0] = t0[pf];
      mg[row][h * 3 + 1] = t1[pf];
      mg[row][h * 3 + 2] = t2[pf];
    }
  }
  __syncthreads();
  if (t < 128) {
    const float s3 = mg[t][3], s4 = mg[t][4], s5 = mg[t][5];
    float s0 = mg[t][0], s1 = mg[t][1], s2 = mg[t][2];
    INSERT3(s0, s1, s2, s3);
    INSERT3(s0, s1, s2, s4);
    INSERT3(s0, s1, s2, s5);
    float* dst = part + ((size_t)c * NROWS + rowBase + t) * 3;
    __builtin_nontemporal_store(s0, dst + 0);
    __builtin_nontemporal_store(s1, dst + 1);
    __builtin_nontemporal_store(s2, dst + 2);
  }
}

// ---- stage2: merge S partial triples per row, sqrt + softmin, write score ----
__global__ __launch_bounds__(256) void dsvdd_stage2(const float* __restrict__ part,
                                                    const float* __restrict__ featg,
                                                    float* __restrict__ out, int S) {
  const int row = blockIdx.x * 256 + threadIdx.x;
  if (row >= NROWS) return;
  float s0 = -3.0e38f, s1 = -3.0e38f, s2 = -3.0e38f;
  for (int c = 0; c < S; ++c) {
    const float* p = part + ((size_t)c * NROWS + row) * 3;
    INSERT3(s0, s1, s2, p[0]);
    INSERT3(s0, s1, s2, p[1]);
    INSERT3(s0, s1, s2, p[2]);
  }
  const float feat = featg[row];
  const float d0 = sqrtf(fmaxf(feat - 2.f * s0, 0.f));
  const float d1 = sqrtf(fmaxf(feat - 2.f * s1, 0.f));
  const float d2 = sqrtf(fmaxf(feat - 2.f * s2, 0.f));
  const float w0 = 1.0f / (1.0f + __expf(d0 - d1) + __expf(d0 - d2));
  out[row] = w0 * d0;
}

extern "C" void kernel_launch(void* const* d_in, const int* in_sizes, int n_in,
                              void* d_out, int out_size, void* d_ws, size_t ws_size,
                              hipStream_t stream) {
  (void)in_sizes; (void)n_in; (void)out_size;
  const float* phi = (const float*)d_in[0];
  const float* Cb = (const float*)d_in[1];
  float* out = (float*)d_out;
  unsigned char* CT2 = (unsigned char*)d_ws;               // 819200 B
  float* featg = (float*)((unsigned char*)d_ws + 819200);  // 200704 B
  float* partp = (float*)((unsigned char*)d_ws + 819200 + 200704);
  const size_t base = 819200 + 200704;
  int S = 1;
  if (ws_size >= base + (size_t)5 * NROWS * 12) S = 5;
  else if (ws_size >= base + (size_t)2 * NROWS * 12) S = 2;
  const int nT = N_TILES_TOT / S;
  dsvdd_prep<<<50, 256, 0, stream>>>(Cb, CT2);
  dsvdd_stage1<<<dim3(392, S), 256, 0, stream>>>(phi, CT2, partp, featg, nT);
  dsvdd_stage2<<<196, 256, 0, stream>>>(partp, featg, out, S);
}

// Round 13
// 64.695 us; speedup vs baseline: 1.3818x; 1.3818x over previous
//
#include <hip/hip_runtime.h>
#include <stdint.h>

// DSVDD fused: dist = sqrt(||phi||^2 + ||c||^2 - 2 phi.c), top-3 smallest, softmin score.
// bf16 MFMA computes S = phi.c - ||c||^2/2 (centers folded into K-pad 112->128),
// track top-3 LARGEST S per row == 3 smallest distances.
// R13: OCCUPANCY push. Every 2-blocks/CU variant stalls at ~57us (8 waves/CU can't
// cover af latency: 1240cy MFMA per tile-round vs 3400cy wall). This round: 32KB LDS
// total (phi prologue staged into the CT dbuf itself, then reused as the 2-tile ring;
// merge scratch aliased), launch_bounds(256,4), lean registers (bg 64 + af temp, no
// reg double-buffer) -> 4 blocks/CU = 16 waves. Counted vmcnt(4), 2 barriers/tile.

typedef short s16x8 __attribute__((ext_vector_type(8)));
typedef float fx4 __attribute__((ext_vector_type(4)));

#define M_TOT 3136
#define CC 112
#define NROWS 50176
#define N_TILES_TOT 50  // 3200 m / 64 per tile; tile bytes = 64*256 = 16384

__device__ __forceinline__ unsigned short f2bf(float x) {
  unsigned u = __float_as_uint(x);
  u += 0x7fffu + ((u >> 16) & 1u);  // RNE
  return (unsigned short)(u >> 16);
}

__device__ __forceinline__ void async16(const void* g, void* l) {
  __builtin_amdgcn_global_load_lds(
      (const __attribute__((address_space(1))) unsigned int*)g,
      (__attribute__((address_space(3))) unsigned int*)l, 16, 0, 0);
}

// insert v into descending triple (t0 >= t1 >= t2), keep 3 largest. 3 VALU ops.
#define INSERT3(T0, T1, T2, V)                                  \
  do {                                                          \
    const float _a0 = (T0), _a1 = (T1), _v = (V);               \
    (T0) = fmaxf(_a0, _v);                                      \
    (T1) = __builtin_amdgcn_fmed3f(_a0, _a1, _v);               \
    (T2) = __builtin_amdgcn_fmed3f(_a1, (T2), _v);              \
  } while (0)

// ---- prep: CT2[tile][f][ks][lane] 16B slots, fragment-ordered for MFMA A-operand ----
// slot value: 8 bf16 = CT[m = tile*64+f*16+(lane&15)][k = ks*32+(lane>>4)*8 + 0..7]
// where CT[m][k] = C_bank[k][m] (k<112); -||c_m||^2/8 (112<=k<116, sentinel -2500); 0 else.
__global__ __launch_bounds__(256) void dsvdd_prep(const float* __restrict__ Cb,
                                                  unsigned char* __restrict__ CT2) {
  const int tile = blockIdx.x;
  __shared__ float partial[256];
  __shared__ float c2s[64];  // pre-scaled fold value per local m
  const int tm = threadIdx.x & 63;
  const int seg = threadIdx.x >> 6;
  const int m = tile * 64 + tm;
  float ss = 0.f;
  if (m < M_TOT) {
    for (int k = seg * 28; k < seg * 28 + 28; ++k) {
      const float x = Cb[(size_t)k * M_TOT + m];
      ss += x * x;
    }
  }
  partial[threadIdx.x] = ss;
  __syncthreads();
  if (seg == 0) {
    const float c2 = partial[tm] + partial[64 + tm] + partial[128 + tm] + partial[192 + tm];
    c2s[tm] = (m < M_TOT) ? (-0.125f * c2) : -2500.0f;  // sentinel: S ~ -1e4
  }
  __syncthreads();
#pragma unroll
  for (int it = 0; it < 4; ++it) {
    const int s = it * 256 + threadIdx.x;  // 0..1023 slots per tile
    const int f = s >> 8;
    const int ks = (s >> 6) & 3;
    const int l = s & 63;
    const int mloc = f * 16 + (l & 15);
    const int mm = tile * 64 + mloc;
    const bool mv = (mm < M_TOT);
    const int k0 = ks * 32 + (l >> 4) * 8;
    float v[8];
#pragma unroll
    for (int j = 0; j < 8; ++j) {
      const int k = k0 + j;
      float x = 0.f;
      if (k < CC) x = mv ? Cb[(size_t)k * M_TOT + mm] : 0.f;
      else if (k < 116) x = c2s[mloc];
      v[j] = x;
    }
    uint4 pk;
    pk.x = (unsigned)f2bf(v[0]) | ((unsigned)f2bf(v[1]) << 16);
    pk.y = (unsigned)f2bf(v[2]) | ((unsigned)f2bf(v[3]) << 16);
    pk.z = (unsigned)f2bf(v[4]) | ((unsigned)f2bf(v[5]) << 16);
    pk.w = (unsigned)f2bf(v[6]) | ((unsigned)f2bf(v[7]) << 16);
    *(uint4*)(CT2 + (size_t)tile * 16384 + (size_t)s * 16) = pk;
  }
}

// ---- stage1: block = 128 rows x nT tiles of 64 m; 4 waves = 2 row-groups x 2 m-halves.
// LDS = 32KB: phi fragments (prologue) -> 2x16KB CT tile ring (main) -> merge (epilogue).
__global__ __launch_bounds__(256, 4) void dsvdd_stage1(const float* __restrict__ phi,
                                                       const unsigned char* __restrict__ CT2,
                                                       float* __restrict__ part,
                                                       float* __restrict__ featg, int nT) {
  __shared__ __align__(16) unsigned char lds[32768];
  float(*const mg)[8] = (float(*)[8])lds;  // epilogue alias (4.25KB)

  const int t = threadIdx.x;
  const int lane = t & 63;
  const int w = t >> 6;
  const int g = w >> 1;  // row-group: rows [g*64, g*64+64)
  const int h = w & 1;   // m-half: fragments f = h*2, h*2+1
  const int cq = lane & 15;
  const int kq = lane >> 4;
  const int c = blockIdx.y;
  const int tile0 = c * nT;
  const int bid = (int)blockIdx.x;
  const long rowBase = (long)bid * 128;
  const bool needF = (c == 0);

  // ---- coalesced phi prologue: 2 threads/row read 448B runs, write bf16 frag slots ----
  {
    const int r = t >> 1;
    const int h2 = t & 1;
    const float* src = phi + (size_t)(rowBase + r) * CC + h2 * 56;
    unsigned char* const base = lds + ((r >> 4) * 4096);  // frag (g*4+pf) = r>>4
    const int pcq = r & 15;
    float ss = 0.f;
#pragma unroll
    for (int j = 0; j < 7; ++j) {
      const int k0 = h2 * 56 + j * 8;
      const int ks = k0 >> 5;
      const int kqw = (k0 >> 3) & 3;
      const float4 a = *(const float4*)(src + j * 8);
      const float4 b = *(const float4*)(src + j * 8 + 4);
      ss += a.x * a.x + a.y * a.y + a.z * a.z + a.w * a.w;
      ss += b.x * b.x + b.y * b.y + b.z * b.z + b.w * b.w;
      uint4 pk;
      pk.x = (unsigned)f2bf(a.x) | ((unsigned)f2bf(a.y) << 16);
      pk.y = (unsigned)f2bf(a.z) | ((unsigned)f2bf(a.w) << 16);
      pk.z = (unsigned)f2bf(b.x) | ((unsigned)f2bf(b.y) << 16);
      pk.w = (unsigned)f2bf(b.z) | ((unsigned)f2bf(b.w) << 16);
      *(uint4*)(base + ks * 1024 + (kqw * 16 + pcq) * 16) = pk;
    }
    {  // K-pad: h2==0 -> slot(ks=3,kq=2) = {1,1,1,1,0,0,0,0}; h2==1 -> slot(3,3) = 0
      uint4 pk;
      if (h2 == 0) { pk.x = 0x3f803f80u; pk.y = 0x3f803f80u; pk.z = 0u; pk.w = 0u; }
      else { pk.x = pk.y = pk.z = pk.w = 0u; }
      *(uint4*)(base + 3 * 1024 + ((2 + h2) * 16 + pcq) * 16) = pk;
    }
    ss += __shfl_xor(ss, 1);
    if (needF && h2 == 0) featg[rowBase + r] = ss;
  }
  __syncthreads();

  // ---- extract bg fragments to registers (64 VGPR/wave) ----
  s16x8 bg[4][4];  // [ks][pf]
#pragma unroll
  for (int ks = 0; ks < 4; ++ks)
#pragma unroll
    for (int pf = 0; pf < 4; ++pf)
      bg[ks][pf] = *(const s16x8*)(lds + ((g * 4 + pf) * 4 + ks) * 1024 + lane * 16);
  __syncthreads();  // phi reads done; lds becomes the CT tile ring

// each wave DMAs its 4KB quarter of one 16KB tile
#define STAGE(BUF, TIDX)                                                        \
  do {                                                                          \
    const unsigned char* _g =                                                   \
        CT2 + (size_t)(TIDX)*16384 + w * 4096 + (size_t)lane * 16;              \
    unsigned char* _l = lds + (BUF)*16384 + w * 4096;                           \
    _Pragma("unroll") for (int i = 0; i < 4; ++i)                               \
        async16(_g + i * 1024, _l + i * 1024);                                  \
  } while (0)

#define COMPUTE(BUF)                                                            \
  do {                                                                          \
    const unsigned char* _rd = lds + (BUF)*16384 + h * 8192 + lane * 16;        \
    const fx4 _zz = {0.f, 0.f, 0.f, 0.f};                                       \
    _Pragma("unroll") for (int mf = 0; mf < 2; ++mf) {                          \
      s16x8 af[4];                                                              \
      _Pragma("unroll") for (int ks = 0; ks < 4; ++ks)                          \
          af[ks] = *(const s16x8*)(_rd + mf * 4096 + ks * 1024);                \
      fx4 acc[4];                                                               \
      _Pragma("unroll") for (int ks = 0; ks < 4; ++ks)                          \
          _Pragma("unroll") for (int pf = 0; pf < 4; ++pf)                      \
              acc[pf] = __builtin_amdgcn_mfma_f32_16x16x32_bf16(                \
                  af[ks], bg[ks][pf], (ks == 0) ? _zz : acc[pf], 0, 0, 0);      \
      _Pragma("unroll") for (int pf = 0; pf < 4; ++pf)                          \
          _Pragma("unroll") for (int rg = 0; rg < 4; ++rg)                      \
              INSERT3(t0[pf], t1[pf], t2[pf], acc[pf][rg]);                     \
    }                                                                           \
  } while (0)

#define FENCE() __builtin_amdgcn_sched_barrier(0)

  float t0[4], t1[4], t2[4];
#pragma unroll
  for (int pf = 0; pf < 4; ++pf) t0[pf] = t1[pf] = t2[pf] = -3.0e38f;

  // staggered tile order: tile(tt) = tile0 + (bid + tt) % nT
  {
    const int j0 = bid % nT;
    const int j1 = (bid + 1) % nT;
    STAGE(0, tile0 + j0);
    STAGE(1, tile0 + j1);
  }
  for (int tt = 0; tt < nT; ++tt) {
    if (tt + 1 < nT) {
      asm volatile("s_waitcnt vmcnt(4)" ::: "memory");  // this tile's 4 DMAs done
    } else {
      asm volatile("s_waitcnt vmcnt(0)" ::: "memory");  // last tile: drain
    }
    FENCE();
    __builtin_amdgcn_s_barrier();  // all waves' quarters landed
    FENCE();
    COMPUTE(tt & 1);
    FENCE();
    __builtin_amdgcn_s_barrier();  // all waves done reading this buffer
    FENCE();
    if (tt + 2 < nT) STAGE(tt & 1, tile0 + (bid + tt + 2) % nT);
  }
#undef STAGE
#undef COMPUTE
#undef FENCE

  // ---- merge the 4 kq groups within each wave ----
#pragma unroll
  for (int pf = 0; pf < 4; ++pf) {
#pragma unroll
    for (int off = 16; off < 64; off <<= 1) {
      const float b0 = __shfl_xor(t0[pf], off);
      const float b1 = __shfl_xor(t1[pf], off);
      const float b2 = __shfl_xor(t2[pf], off);
      INSERT3(t0[pf], t1[pf], t2[pf], b0);
      INSERT3(t0[pf], t1[pf], t2[pf], b1);
      INSERT3(t0[pf], t1[pf], t2[pf], b2);
    }
  }
  __syncthreads();  // all tile reads done; safe to alias mg onto lds
  if (kq == 0) {
#pragma unroll
    for (int pf = 0; pf < 4; ++pf) {
      const int row = g * 64 + pf * 16 + cq;
      mg[row][h * 3 + 0] = t0[pf];
      mg[row][h * 3 + 1] = t1[pf];
      mg[row][h * 3 + 2] = t2[pf];
    }
  }
  __syncthreads();
  if (t < 128) {
    float s0 = mg[t][0], s1 = mg[t][1], s2 = mg[t][2];
    INSERT3(s0, s1, s2, mg[t][3]);
    INSERT3(s0, s1, s2, mg[t][4]);
    INSERT3(s0, s1, s2, mg[t][5]);
    float* dst = part + ((size_t)c * NROWS + rowBase + t) * 3;
    dst[0] = s0; dst[1] = s1; dst[2] = s2;
  }
}

// ---- stage2: merge S partial triples per row, sqrt + softmin, write score ----
__global__ __launch_bounds__(256) void dsvdd_stage2(const float* __restrict__ part,
                                                    const float* __restrict__ featg,
                                                    float* __restrict__ out, int S) {
  const int row = blockIdx.x * 256 + threadIdx.x;
  if (row >= NROWS) return;
  float s0 = -3.0e38f, s1 = -3.0e38f, s2 = -3.0e38f;
  for (int c = 0; c < S; ++c) {
    const float* p = part + ((size_t)c * NROWS + row) * 3;
    INSERT3(s0, s1, s2, p[0]);
    INSERT3(s0, s1, s2, p[1]);
    INSERT3(s0, s1, s2, p[2]);
  }
  const float feat = featg[row];
  const float d0 = sqrtf(fmaxf(feat - 2.f * s0, 0.f));
  const float d1 = sqrtf(fmaxf(feat - 2.f * s1, 0.f));
  const float d2 = sqrtf(fmaxf(feat - 2.f * s2, 0.f));
  const float w0 = 1.0f / (1.0f + __expf(d0 - d1) + __expf(d0 - d2));
  out[row] = w0 * d0;
}

extern "C" void kernel_launch(void* const* d_in, const int* in_sizes, int n_in,
                              void* d_out, int out_size, void* d_ws, size_t ws_size,
                              hipStream_t stream) {
  (void)in_sizes; (void)n_in; (void)out_size;
  const float* phi = (const float*)d_in[0];
  const float* Cb = (const float*)d_in[1];
  float* out = (float*)d_out;
  unsigned char* CT2 = (unsigned char*)d_ws;               // 819200 B
  float* featg = (float*)((unsigned char*)d_ws + 819200);  // 200704 B
  float* partp = (float*)((unsigned char*)d_ws + 819200 + 200704);
  const size_t base = 819200 + 200704;
  int S = 1;
  if (ws_size >= base + (size_t)5 * NROWS * 12) S = 5;
  else if (ws_size >= base + (size_t)2 * NROWS * 12) S = 2;
  const int nT = N_TILES_TOT / S;
  dsvdd_prep<<<50, 256, 0, stream>>>(Cb, CT2);
  dsvdd_stage1<<<dim3(392, S), 256, 0, stream>>>(phi, CT2, partp, featg, nT);
  dsvdd_stage2<<<196, 256, 0, stream>>>(partp, featg, out, S);
}